// Round 6
// baseline (2965.288 us; speedup 1.0000x reference)
//
#include <hip/hip_runtime.h>
#include <math.h>

#define BOX   256
#define NPTS  50000
#define LATD  10
#define NEUR  32
#define NLAY  3
#define BATCH 16

#define ATPB  256
#define ABLKX ((NPTS + ATPB - 1)/ATPB)     // 196

#define CELLS_X 64                          // 4x4-px cells
#define CELLS   (CELLS_X*CELLS_X)           // 4096 per image
#define PREF_STRIDE 4104                    // 4096 + total + pad (16B-aligned)

#define IMG_ELEMS (BATCH*BOX*BOX)          // 1,048,576
#define OFF_IMG2  (IMG_ELEMS)
#define OFF_PROJ  (2*IMG_ELEMS)
#define OFF_POS   (OFF_PROJ + BATCH*NPTS*2)
#define OFF_RES   (OFF_POS  + BATCH*NPTS*3)

// ws layout (ints):   counts[16*4096] | prefix[16*4104] | cursor[16*4096]
// then (16B aligned): records float4[16*50000]
#define WS_COUNTS 0
#define WS_PREFIX (BATCH*CELLS)                     // 65536
#define WS_CURSOR (WS_PREFIX + BATCH*PREF_STRIDE)   // 65536+65664=131200
#define WS_INTS   (WS_CURSOR + BATCH*CELLS)         // 196736 ints = 786944 B (div 16)

__device__ __forceinline__ float fast_tanh(float x) {
    return 1.0f - 2.0f / (__expf(2.0f * x) + 1.0f);
}

// ---------------- kernel A: per-point MLP + outputs + cell counts ----------------
__global__ __launch_bounds__(ATPB) void mlp_fwd(
    const float* __restrict__ z, const float* __restrict__ r,
    const float* __restrict__ pos_param,
    const float* __restrict__ lin0_w, const float* __restrict__ deform_w,
    const float* __restrict__ deform_b, const float* __restrict__ lin1a_w,
    const float* __restrict__ lin1b_w, const int* __restrict__ dflag,
    float* __restrict__ out, int* __restrict__ counts)
{
    __shared__ float s_zpart[NEUR];
    const int b = blockIdx.y, tid = threadIdx.x;

    if (tid < NEUR) {
        float acc = 0.f;
        #pragma unroll
        for (int j = 0; j < LATD-1; j++)
            acc = fmaf(lin0_w[tid*12 + 3 + j], z[b*LATD + j], acc);
        s_zpart[tid] = acc;
    }
    __syncthreads();

    const int n = blockIdx.x*ATPB + tid;
    if (n >= NPTS) return;
    const int dd = *dflag;

    const float r00 = r[b*9+0], r01 = r[b*9+1];
    const float r10 = r[b*9+3], r11 = r[b*9+4];
    const float r20 = r[b*9+6], r21 = r[b*9+7];

    const float p0 = pos_param[n*3+0];
    const float p1 = pos_param[n*3+1];
    const float p2 = pos_param[n*3+2];

    float res0 = 0.f, res1 = 0.f, res2 = 0.f;
    if (dd > 0) {
        float h[NEUR], nh[NEUR];
        #pragma unroll
        for (int o = 0; o < NEUR; o++) {
            float acc = s_zpart[o];
            acc = fmaf(lin0_w[o*12+0], p0, acc);
            acc = fmaf(lin0_w[o*12+1], p1, acc);
            acc = fmaf(lin0_w[o*12+2], p2, acc);
            h[o] = acc;
        }
        #pragma unroll 1
        for (int l = 0; l < NLAY; l++) {
            const float* __restrict__ W  = deform_w + l*NEUR*NEUR;
            const float* __restrict__ bb = deform_b + l*NEUR;
            #pragma unroll
            for (int o = 0; o < NEUR; o++) {
                float acc = bb[o];
                #pragma unroll
                for (int j = 0; j < NEUR; j++)
                    acc = fmaf(W[o*NEUR + j], h[j], acc);
                nh[o] = fmaxf(acc, 0.f) + h[o];
            }
            #pragma unroll
            for (int o = 0; o < NEUR; o++) h[o] = nh[o];
        }
        float t0 = 0.f, t1 = 0.f, t2 = 0.f;
        #pragma unroll
        for (int j = 0; j < NEUR; j++) {
            t0 = fmaf(lin1a_w[0*NEUR + j], h[j], t0);
            t1 = fmaf(lin1a_w[1*NEUR + j], h[j], t1);
            t2 = fmaf(lin1a_w[2*NEUR + j], h[j], t2);
        }
        t0 = fast_tanh(t0); t1 = fast_tanh(t1); t2 = fast_tanh(t2);
        res0 = fmaf(t0, lin1b_w[0], fmaf(t1, lin1b_w[1], t2*lin1b_w[2]));
        res1 = fmaf(t0, lin1b_w[3], fmaf(t1, lin1b_w[4], t2*lin1b_w[5]));
        res2 = fmaf(t0, lin1b_w[6], fmaf(t1, lin1b_w[7], t2*lin1b_w[8]));
    }

    const float pos0 = p0 + res0, pos1 = p1 + res1, pos2 = p2 + res2;
    const float proj0 = fmaf(pos0, r00, fmaf(pos1, r10, pos2*r20));
    const float proj1 = fmaf(pos0, r01, fmaf(pos1, r11, pos2*r21));

    const long long bn = (long long)b*NPTS + n;
    out[OFF_PROJ + bn*2 + 0] = proj0;
    out[OFF_PROJ + bn*2 + 1] = proj1;
    out[OFF_POS  + bn*3 + 0] = pos0;
    out[OFF_POS  + bn*3 + 1] = pos1;
    out[OFF_POS  + bn*3 + 2] = pos2;
    out[OFF_RES  + bn*3 + 0] = res0;
    out[OFF_RES  + bn*3 + 1] = res1;
    out[OFF_RES  + bn*3 + 2] = res2;

    // bin count: cell of clamped center pixel
    const float px0 = (proj0 + 0.5f) * (float)(BOX-1);
    const float px1 = (proj1 + 0.5f) * (float)(BOX-1);
    const int c0 = (int)fminf(fmaxf(floorf(px0 + 0.5f), 0.f), 255.f);
    const int c1 = (int)fminf(fmaxf(floorf(px1 + 0.5f), 0.f), 255.f);
    atomicAdd(&counts[b*CELLS + (c0>>2)*CELLS_X + (c1>>2)], 1);
}

// ---------------- kernel B: exclusive prefix scan of 4096 cells per image ----------------
__global__ __launch_bounds__(1024) void scan_cells(
    const int* __restrict__ counts, int* __restrict__ prefix, int* __restrict__ cursor)
{
    __shared__ int lds[1024];
    const int img = blockIdx.x, t = threadIdx.x;
    const int4 v = ((const int4*)(counts + img*CELLS))[t];
    const int s0 = v.x, s1 = s0 + v.y, s2 = s1 + v.z, s3 = s2 + v.w;
    lds[t] = s3;
    __syncthreads();
    #pragma unroll 1
    for (int off = 1; off < 1024; off <<= 1) {
        const int add = (t >= off) ? lds[t - off] : 0;
        __syncthreads();
        lds[t] += add;
        __syncthreads();
    }
    const int incl = lds[t];
    const int base = incl - s3;            // exclusive over preceding threads
    const int4 p = make_int4(base, base + s0, base + s1, base + s2);
    ((int4*)(prefix + img*PREF_STRIDE))[t] = p;
    ((int4*)(cursor + img*CELLS))[t] = p;
    if (t == 1023) prefix[img*PREF_STRIDE + CELLS] = incl;   // total (=NPTS)
}

// ---------------- kernel C: scatter point records into cell-sorted array ----------------
__global__ __launch_bounds__(ATPB) void scatter_pts(
    const float* __restrict__ z, const float* __restrict__ amp,
    const float* __restrict__ linamp_w, const float* __restrict__ linamp_b,
    const float* __restrict__ out, int* __restrict__ cursor, float4* __restrict__ recs)
{
    const int b = blockIdx.y;
    const int n = blockIdx.x*ATPB + threadIdx.x;
    if (n >= NPTS) return;

    const float ampv  = amp[0];
    const float zlast = z[b*LATD + LATD-1];
    const long long bn = (long long)b*NPTS + n;
    const float proj0 = out[OFF_PROJ + bn*2 + 0];
    const float proj1 = out[OFF_PROJ + bn*2 + 1];

    const float lo = fmaf(zlast, linamp_w[n], linamp_b[n]);
    const float a  = ampv / (1.0f + __expf(-lo));

    const float px0 = (proj0 + 0.5f) * (float)(BOX-1);
    const float px1 = (proj1 + 0.5f) * (float)(BOX-1);
    const int c0 = (int)fminf(fmaxf(floorf(px0 + 0.5f), 0.f), 255.f);
    const int c1 = (int)fminf(fmaxf(floorf(px1 + 0.5f), 0.f), 255.f);
    const int cell = (c0>>2)*CELLS_X + (c1>>2);

    const int idx = atomicAdd(&cursor[b*CELLS + cell], 1);
    recs[(long long)b*NPTS + idx] = make_float4(px0, px1, a, 0.f);
}

// ---------------- kernel D: gather — one wave per 4x16-px block ----------------
__global__ __launch_bounds__(64) void gather_img(
    const float4* __restrict__ recs, const int* __restrict__ prefix,
    float* __restrict__ out)
{
    const int b = blockIdx.y;
    const int by = blockIdx.x >> 4;          // 0..63 (4-row blocks)
    const int bx = blockIdx.x & 15;          // 0..15 (16-col blocks)
    const int tid = threadIdx.x;
    const int y = by*4  + (tid >> 4);
    const int x = bx*16 + (tid & 15);
    const float yf = (float)y, xf = (float)x;
    const float inv2s2 = 1.0f/(2.0f*1.5f*1.5f);

    const int cyl = max(by - 1, 0),  cyh = min(by + 1, CELLS_X-1);
    const int cxl = max(4*bx - 1, 0), cxh = min(4*bx + 4, CELLS_X-1);

    const int* __restrict__ P = prefix + b*PREF_STRIDE;
    const float4* __restrict__ R = recs + (long long)b*NPTS;

    float acc = 0.f;
    #pragma unroll 1
    for (int cy = cyl; cy <= cyh; cy++) {
        const int s = P[cy*CELLS_X + cxl];
        const int e = P[cy*CELLS_X + cxh + 1];
        #pragma unroll 1
        for (int rr = s; rr < e; rr++) {
            const float4 rc = R[rr];                  // wave-uniform -> broadcast
            const float dy = yf - rc.x;
            const float dx = xf - rc.y;
            const float c0 = floorf(rc.x + 0.5f);
            const float c1 = floorf(rc.y + 0.5f);
            const bool m = (fabsf(yf - c0) <= 4.0f) & (fabsf(xf - c1) <= 4.0f);
            const float w = __expf(-(dy*dy + dx*dx) * inv2s2) * rc.z;
            acc += m ? w : 0.0f;
        }
    }

    const size_t ip = (size_t)b*BOX*BOX + y*BOX + x;
    out[ip] = acc;
    out[OFF_IMG2 + ip] = acc;
}

extern "C" void kernel_launch(void* const* d_in, const int* in_sizes, int n_in,
                              void* d_out, int out_size, void* d_ws, size_t ws_size,
                              hipStream_t stream)
{
    const float* z        = (const float*)d_in[0];
    const float* r        = (const float*)d_in[1];
    const float* posp     = (const float*)d_in[2];
    const float* amp      = (const float*)d_in[3];
    const float* lin0_w   = (const float*)d_in[4];
    const float* deform_w = (const float*)d_in[5];
    const float* deform_b = (const float*)d_in[6];
    const float* lin1a_w  = (const float*)d_in[7];
    const float* lin1b_w  = (const float*)d_in[8];
    const float* linamp_w = (const float*)d_in[9];
    const float* linamp_b = (const float*)d_in[10];
    const int*   dflag    = (const int*)d_in[11];
    float* out = (float*)d_out;

    int* ws_i      = (int*)d_ws;
    int* counts    = ws_i + WS_COUNTS;
    int* prefix    = ws_i + WS_PREFIX;
    int* cursor    = ws_i + WS_CURSOR;
    float4* recs   = (float4*)((char*)d_ws + (size_t)WS_INTS*sizeof(int));

    hipMemsetAsync(counts, 0, (size_t)BATCH*CELLS*sizeof(int), stream);

    dim3 gridA(ABLKX, BATCH);
    mlp_fwd<<<gridA, ATPB, 0, stream>>>(z, r, posp, lin0_w, deform_w, deform_b,
                                        lin1a_w, lin1b_w, dflag, out, counts);

    scan_cells<<<BATCH, 1024, 0, stream>>>(counts, prefix, cursor);

    scatter_pts<<<gridA, ATPB, 0, stream>>>(z, amp, linamp_w, linamp_b,
                                            out, cursor, recs);

    dim3 gridD(64*16, BATCH);
    gather_img<<<gridD, 64, 0, stream>>>(recs, prefix, out);
}

// Round 7
// 976.891 us; speedup vs baseline: 3.0354x; 3.0354x over previous
//
#include <hip/hip_runtime.h>
#include <math.h>

#define BOX   256
#define NPTS  50000
#define LATD  10
#define NEUR  32
#define NLAY  3
#define BATCH 16

#define ATPB  256
#define ABLKX ((NPTS + ATPB - 1)/ATPB)     // 196

#define CELLS_X 64                          // 4x4-px cells
#define CELLS   (CELLS_X*CELLS_X)           // 4096 per image
#define PREF_STRIDE 4104                    // 4096 + total + pad (16B-aligned)

#define IMG_ELEMS (BATCH*BOX*BOX)          // 1,048,576
#define OFF_IMG2  (IMG_ELEMS)
#define OFF_PROJ  (2*IMG_ELEMS)
#define OFF_POS   (OFF_PROJ + BATCH*NPTS*2)
#define OFF_RES   (OFF_POS  + BATCH*NPTS*3)

// ws layout (ints):   counts[16*4096] | prefix[16*4104] | cursor[16*4096]
// then (16B aligned): records float4[16*50000]   -> total ~13.6 MB
#define WS_COUNTS 0
#define WS_PREFIX (BATCH*CELLS)
#define WS_CURSOR (WS_PREFIX + BATCH*PREF_STRIDE)
#define WS_INTS   (WS_CURSOR + BATCH*CELLS)

__device__ __forceinline__ float fast_tanh(float x) {
    return 1.0f - 2.0f / (__expf(2.0f * x) + 1.0f);
}

__device__ __forceinline__ float bcast(float v, int j) {
    return __int_as_float(__builtin_amdgcn_readlane(__float_as_int(v), j));
}

// ---------------- kernel A: per-point MLP + outputs + cell counts ----------------
__global__ __launch_bounds__(ATPB) void mlp_fwd(
    const float* __restrict__ z, const float* __restrict__ r,
    const float* __restrict__ pos_param,
    const float* __restrict__ lin0_w, const float* __restrict__ deform_w,
    const float* __restrict__ deform_b, const float* __restrict__ lin1a_w,
    const float* __restrict__ lin1b_w, const int* __restrict__ dflag,
    float* __restrict__ out, int* __restrict__ counts)
{
    __shared__ float s_zpart[NEUR];
    const int b = blockIdx.y, tid = threadIdx.x;

    if (tid < NEUR) {
        float acc = 0.f;
        #pragma unroll
        for (int j = 0; j < LATD-1; j++)
            acc = fmaf(lin0_w[tid*12 + 3 + j], z[b*LATD + j], acc);
        s_zpart[tid] = acc;
    }
    __syncthreads();

    const int n = blockIdx.x*ATPB + tid;
    if (n >= NPTS) return;
    const int dd = *dflag;

    const float r00 = r[b*9+0], r01 = r[b*9+1];
    const float r10 = r[b*9+3], r11 = r[b*9+4];
    const float r20 = r[b*9+6], r21 = r[b*9+7];

    const float p0 = pos_param[n*3+0];
    const float p1 = pos_param[n*3+1];
    const float p2 = pos_param[n*3+2];

    float res0 = 0.f, res1 = 0.f, res2 = 0.f;
    if (dd > 0) {
        float h[NEUR], nh[NEUR];
        #pragma unroll
        for (int o = 0; o < NEUR; o++) {
            float acc = s_zpart[o];
            acc = fmaf(lin0_w[o*12+0], p0, acc);
            acc = fmaf(lin0_w[o*12+1], p1, acc);
            acc = fmaf(lin0_w[o*12+2], p2, acc);
            h[o] = acc;
        }
        #pragma unroll 1
        for (int l = 0; l < NLAY; l++) {
            const float* __restrict__ W  = deform_w + l*NEUR*NEUR;
            const float* __restrict__ bb = deform_b + l*NEUR;
            #pragma unroll
            for (int o = 0; o < NEUR; o++) {
                float acc = bb[o];
                #pragma unroll
                for (int j = 0; j < NEUR; j++)
                    acc = fmaf(W[o*NEUR + j], h[j], acc);
                nh[o] = fmaxf(acc, 0.f) + h[o];
            }
            #pragma unroll
            for (int o = 0; o < NEUR; o++) h[o] = nh[o];
        }
        float t0 = 0.f, t1 = 0.f, t2 = 0.f;
        #pragma unroll
        for (int j = 0; j < NEUR; j++) {
            t0 = fmaf(lin1a_w[0*NEUR + j], h[j], t0);
            t1 = fmaf(lin1a_w[1*NEUR + j], h[j], t1);
            t2 = fmaf(lin1a_w[2*NEUR + j], h[j], t2);
        }
        t0 = fast_tanh(t0); t1 = fast_tanh(t1); t2 = fast_tanh(t2);
        res0 = fmaf(t0, lin1b_w[0], fmaf(t1, lin1b_w[1], t2*lin1b_w[2]));
        res1 = fmaf(t0, lin1b_w[3], fmaf(t1, lin1b_w[4], t2*lin1b_w[5]));
        res2 = fmaf(t0, lin1b_w[6], fmaf(t1, lin1b_w[7], t2*lin1b_w[8]));
    }

    const float pos0 = p0 + res0, pos1 = p1 + res1, pos2 = p2 + res2;
    const float proj0 = fmaf(pos0, r00, fmaf(pos1, r10, pos2*r20));
    const float proj1 = fmaf(pos0, r01, fmaf(pos1, r11, pos2*r21));

    const long long bn = (long long)b*NPTS + n;
    out[OFF_PROJ + bn*2 + 0] = proj0;
    out[OFF_PROJ + bn*2 + 1] = proj1;
    out[OFF_POS  + bn*3 + 0] = pos0;
    out[OFF_POS  + bn*3 + 1] = pos1;
    out[OFF_POS  + bn*3 + 2] = pos2;
    out[OFF_RES  + bn*3 + 0] = res0;
    out[OFF_RES  + bn*3 + 1] = res1;
    out[OFF_RES  + bn*3 + 2] = res2;

    const float px0 = (proj0 + 0.5f) * (float)(BOX-1);
    const float px1 = (proj1 + 0.5f) * (float)(BOX-1);
    const int c0 = (int)fminf(fmaxf(floorf(px0 + 0.5f), 0.f), 255.f);
    const int c1 = (int)fminf(fmaxf(floorf(px1 + 0.5f), 0.f), 255.f);
    atomicAdd(&counts[b*CELLS + (c0>>2)*CELLS_X + (c1>>2)], 1);
}

// ---------------- kernel B: exclusive prefix scan of 4096 cells per image ----------------
__global__ __launch_bounds__(1024) void scan_cells(
    const int* __restrict__ counts, int* __restrict__ prefix, int* __restrict__ cursor)
{
    __shared__ int lds[1024];
    const int img = blockIdx.x, t = threadIdx.x;
    const int4 v = ((const int4*)(counts + img*CELLS))[t];
    const int s0 = v.x, s1 = s0 + v.y, s2 = s1 + v.z, s3 = s2 + v.w;
    lds[t] = s3;
    __syncthreads();
    #pragma unroll 1
    for (int off = 1; off < 1024; off <<= 1) {
        const int add = (t >= off) ? lds[t - off] : 0;
        __syncthreads();
        lds[t] += add;
        __syncthreads();
    }
    const int incl = lds[t];
    const int base = incl - s3;
    const int4 p = make_int4(base, base + s0, base + s1, base + s2);
    ((int4*)(prefix + img*PREF_STRIDE))[t] = p;
    ((int4*)(cursor + img*CELLS))[t] = p;
    if (t == 1023) prefix[img*PREF_STRIDE + CELLS] = incl;
}

// ---------------- kernel C: scatter point records into cell-sorted array ----------------
__global__ __launch_bounds__(ATPB) void scatter_pts(
    const float* __restrict__ z, const float* __restrict__ amp,
    const float* __restrict__ linamp_w, const float* __restrict__ linamp_b,
    const float* __restrict__ out, int* __restrict__ cursor, float4* __restrict__ recs)
{
    const int b = blockIdx.y;
    const int n = blockIdx.x*ATPB + threadIdx.x;
    if (n >= NPTS) return;

    const float ampv  = amp[0];
    const float zlast = z[b*LATD + LATD-1];
    const long long bn = (long long)b*NPTS + n;
    const float proj0 = out[OFF_PROJ + bn*2 + 0];
    const float proj1 = out[OFF_PROJ + bn*2 + 1];

    const float lo = fmaf(zlast, linamp_w[n], linamp_b[n]);
    const float a  = ampv / (1.0f + __expf(-lo));

    const float px0 = (proj0 + 0.5f) * (float)(BOX-1);
    const float px1 = (proj1 + 0.5f) * (float)(BOX-1);
    const int c0 = (int)fminf(fmaxf(floorf(px0 + 0.5f), 0.f), 255.f);
    const int c1 = (int)fminf(fmaxf(floorf(px1 + 0.5f), 0.f), 255.f);
    const int cell = (c0>>2)*CELLS_X + (c1>>2);

    const int idx = atomicAdd(&cursor[b*CELLS + cell], 1);
    recs[(long long)b*NPTS + idx] = make_float4(px0, px1, a, 0.f);
}

// -------- kernel D: one wave per cell; lanes own 12x16 window (3 px each) --------
__global__ __launch_bounds__(256) void gather_cells(
    const float4* __restrict__ recs, const int* __restrict__ prefix,
    float* __restrict__ out)
{
    const int b    = blockIdx.y;
    const int cell = blockIdx.x*4 + (threadIdx.x >> 6);
    const int lane = threadIdx.x & 63;
    const int cy   = cell >> 6, cx = cell & 63;

    const int* __restrict__ P = prefix + b*PREF_STRIDE;
    const int s = P[cell], e = P[cell + 1];
    if (s >= e) return;                         // wave-uniform

    const int col = lane & 15;                  // window col 0..15
    const int r0  = lane >> 4;                  // base row 0..3; rows r0, r0+4, r0+8
    const int gx  = 4*cx - 4 + col;             // image col of this lane
    const int gy0 = 4*cy - 4 + r0;              // image rows gy0, gy0+4, gy0+8
    const float xf = (float)gx;
    const float y0f = (float)gy0, y1f = y0f + 4.0f, y2f = y0f + 8.0f;
    const float K = -1.4426950408889634f / (2.0f*1.5f*1.5f);   // exp2 scale

    const float4* __restrict__ R = recs + (long long)b*NPTS;
    float a0 = 0.f, a1 = 0.f, a2 = 0.f;

    for (int chunk = s; chunk < e; chunk += 64) {
        float4 rec = make_float4(0.f, 0.f, 0.f, 0.f);
        if (chunk + lane < e) rec = R[chunk + lane];
        const int kmax = min(64, e - chunk);
        for (int j = 0; j < kmax; ++j) {
            const float ry = bcast(rec.x, j);   // row coord (dim0)
            const float rx = bcast(rec.y, j);   // col coord (dim1)
            const float ra = bcast(rec.z, j);

            const float c1f = floorf(rx + 0.5f);   // unclamped centers
            const float c0f = floorf(ry + 0.5f);

            const float dx  = xf - rx;
            float aex = ra * exp2f(dx*dx*K);
            aex = (fabsf(xf - c1f) <= 4.0f) ? aex : 0.f;

            const float dy0 = y0f - ry;
            const float dy1 = y1f - ry;
            const float dy2 = y2f - ry;
            float e0 = exp2f(dy0*dy0*K);
            float e1 = exp2f(dy1*dy1*K);
            float e2 = exp2f(dy2*dy2*K);
            e0 = (fabsf(y0f - c0f) <= 4.0f) ? e0 : 0.f;
            e1 = (fabsf(y1f - c0f) <= 4.0f) ? e1 : 0.f;
            e2 = (fabsf(y2f - c0f) <= 4.0f) ? e2 : 0.f;
            a0 = fmaf(e0, aex, a0);
            a1 = fmaf(e1, aex, a1);
            a2 = fmaf(e2, aex, a2);
        }
    }

    // flush: spread atomics (<=9 writers per pixel)
    if (gx >= 0 && gx < BOX) {
        float* __restrict__ img = out + (size_t)b*BOX*BOX;
        if (a0 != 0.f && gy0     >= 0 && gy0     < BOX) atomicAdd(&img[ gy0     *BOX + gx], a0);
        if (a1 != 0.f && gy0 + 4 >= 0 && gy0 + 4 < BOX) atomicAdd(&img[(gy0 + 4)*BOX + gx], a1);
        if (a2 != 0.f &&                gy0 + 8 < BOX) atomicAdd(&img[(gy0 + 8)*BOX + gx], a2);
    }
}

__global__ __launch_bounds__(256) void copy_img(const float4* __restrict__ src,
                                                float4* __restrict__ dst, int n4)
{
    int i = blockIdx.x*blockDim.x + threadIdx.x;
    if (i < n4) dst[i] = src[i];
}

extern "C" void kernel_launch(void* const* d_in, const int* in_sizes, int n_in,
                              void* d_out, int out_size, void* d_ws, size_t ws_size,
                              hipStream_t stream)
{
    const float* z        = (const float*)d_in[0];
    const float* r        = (const float*)d_in[1];
    const float* posp     = (const float*)d_in[2];
    const float* amp      = (const float*)d_in[3];
    const float* lin0_w   = (const float*)d_in[4];
    const float* deform_w = (const float*)d_in[5];
    const float* deform_b = (const float*)d_in[6];
    const float* lin1a_w  = (const float*)d_in[7];
    const float* lin1b_w  = (const float*)d_in[8];
    const float* linamp_w = (const float*)d_in[9];
    const float* linamp_b = (const float*)d_in[10];
    const int*   dflag    = (const int*)d_in[11];
    float* out = (float*)d_out;

    int* ws_i    = (int*)d_ws;
    int* counts  = ws_i + WS_COUNTS;
    int* prefix  = ws_i + WS_PREFIX;
    int* cursor  = ws_i + WS_CURSOR;
    float4* recs = (float4*)((char*)d_ws + (size_t)WS_INTS*sizeof(int));

    hipMemsetAsync(counts, 0, (size_t)BATCH*CELLS*sizeof(int), stream);
    hipMemsetAsync(out, 0, (size_t)IMG_ELEMS*sizeof(float), stream);

    dim3 gridA(ABLKX, BATCH);
    mlp_fwd<<<gridA, ATPB, 0, stream>>>(z, r, posp, lin0_w, deform_w, deform_b,
                                        lin1a_w, lin1b_w, dflag, out, counts);

    scan_cells<<<BATCH, 1024, 0, stream>>>(counts, prefix, cursor);

    scatter_pts<<<gridA, ATPB, 0, stream>>>(z, amp, linamp_w, linamp_b,
                                            out, cursor, recs);

    dim3 gridD(CELLS/4, BATCH);
    gather_cells<<<gridD, 256, 0, stream>>>(recs, prefix, out);

    const int n4 = IMG_ELEMS/4;
    copy_img<<<(n4 + 255)/256, 256, 0, stream>>>((const float4*)out,
                                                 (float4*)(out + OFF_IMG2), n4);
}

// Round 8
// 497.475 us; speedup vs baseline: 5.9607x; 1.9637x over previous
//
#include <hip/hip_runtime.h>
#include <math.h>

#define BOX   256
#define NPTS  50000
#define LATD  10
#define NEUR  32
#define NLAY  3
#define BATCH 16

#define ATPB  256
#define ABLKX ((NPTS + ATPB - 1)/ATPB)     // 196

#define CELLS_X 64                          // 4x4-px cells
#define CELLS   (CELLS_X*CELLS_X)           // 4096 per image
#define PREF_STRIDE 4104
#define CHUNK   256                         // records per work item
#define WCAP    4608                        // work items cap per image

#define IMG_ELEMS (BATCH*BOX*BOX)
#define OFF_IMG2  (IMG_ELEMS)
#define OFF_PROJ  (2*IMG_ELEMS)
#define OFF_POS   (OFF_PROJ + BATCH*NPTS*2)
#define OFF_RES   (OFF_POS  + BATCH*NPTS*3)

// ws ints: counts[16*4096] | n_work[16] | prefix[16*4104] | cursor[16*4096] | work[16*4608]
// then (16B aligned): recs float4[16*50000]  -> ~13.9 MB total
#define WS_COUNTS 0
#define WS_NWORK  (BATCH*CELLS)                       // 65536
#define WS_PREFIX (WS_NWORK + BATCH)                  // 65552
#define WS_CURSOR (WS_PREFIX + BATCH*PREF_STRIDE)     // 131216
#define WS_WORK   (WS_CURSOR + BATCH*CELLS)           // 196752
#define WS_INTS   (WS_WORK + BATCH*WCAP)              // 270480 (x4 = 1081920 B, 16B-aligned)

__device__ __forceinline__ float fast_tanh(float x) {
    return 1.0f - 2.0f / (__expf(2.0f * x) + 1.0f);
}
__device__ __forceinline__ float bcast(float v, int j) {
    return __int_as_float(__builtin_amdgcn_readlane(__float_as_int(v), j));
}

// ---------------- kernel A: per-point MLP + outputs + cell counts ----------------
__global__ __launch_bounds__(ATPB) void mlp_fwd(
    const float* __restrict__ z, const float* __restrict__ r,
    const float* __restrict__ pos_param,
    const float* __restrict__ lin0_w, const float* __restrict__ deform_w,
    const float* __restrict__ deform_b, const float* __restrict__ lin1a_w,
    const float* __restrict__ lin1b_w, const int* __restrict__ dflag,
    float* __restrict__ out, int* __restrict__ counts)
{
    __shared__ float s_zpart[NEUR];
    const int b = blockIdx.y, tid = threadIdx.x;

    if (tid < NEUR) {
        float acc = 0.f;
        #pragma unroll
        for (int j = 0; j < LATD-1; j++)
            acc = fmaf(lin0_w[tid*12 + 3 + j], z[b*LATD + j], acc);
        s_zpart[tid] = acc;
    }
    __syncthreads();

    const int n = blockIdx.x*ATPB + tid;
    if (n >= NPTS) return;
    const int dd = *dflag;

    const float r00 = r[b*9+0], r01 = r[b*9+1];
    const float r10 = r[b*9+3], r11 = r[b*9+4];
    const float r20 = r[b*9+6], r21 = r[b*9+7];

    const float p0 = pos_param[n*3+0];
    const float p1 = pos_param[n*3+1];
    const float p2 = pos_param[n*3+2];

    float res0 = 0.f, res1 = 0.f, res2 = 0.f;
    if (dd > 0) {
        float h[NEUR], nh[NEUR];
        #pragma unroll
        for (int o = 0; o < NEUR; o++) {
            float acc = s_zpart[o];
            acc = fmaf(lin0_w[o*12+0], p0, acc);
            acc = fmaf(lin0_w[o*12+1], p1, acc);
            acc = fmaf(lin0_w[o*12+2], p2, acc);
            h[o] = acc;
        }
        #pragma unroll 1
        for (int l = 0; l < NLAY; l++) {
            const float* __restrict__ W  = deform_w + l*NEUR*NEUR;
            const float* __restrict__ bb = deform_b + l*NEUR;
            #pragma unroll
            for (int o = 0; o < NEUR; o++) {
                float acc = bb[o];
                #pragma unroll
                for (int j = 0; j < NEUR; j++)
                    acc = fmaf(W[o*NEUR + j], h[j], acc);
                nh[o] = fmaxf(acc, 0.f) + h[o];
            }
            #pragma unroll
            for (int o = 0; o < NEUR; o++) h[o] = nh[o];
        }
        float t0 = 0.f, t1 = 0.f, t2 = 0.f;
        #pragma unroll
        for (int j = 0; j < NEUR; j++) {
            t0 = fmaf(lin1a_w[0*NEUR + j], h[j], t0);
            t1 = fmaf(lin1a_w[1*NEUR + j], h[j], t1);
            t2 = fmaf(lin1a_w[2*NEUR + j], h[j], t2);
        }
        t0 = fast_tanh(t0); t1 = fast_tanh(t1); t2 = fast_tanh(t2);
        res0 = fmaf(t0, lin1b_w[0], fmaf(t1, lin1b_w[1], t2*lin1b_w[2]));
        res1 = fmaf(t0, lin1b_w[3], fmaf(t1, lin1b_w[4], t2*lin1b_w[5]));
        res2 = fmaf(t0, lin1b_w[6], fmaf(t1, lin1b_w[7], t2*lin1b_w[8]));
    }

    const float pos0 = p0 + res0, pos1 = p1 + res1, pos2 = p2 + res2;
    const float proj0 = fmaf(pos0, r00, fmaf(pos1, r10, pos2*r20));
    const float proj1 = fmaf(pos0, r01, fmaf(pos1, r11, pos2*r21));

    const long long bn = (long long)b*NPTS + n;
    out[OFF_PROJ + bn*2 + 0] = proj0;
    out[OFF_PROJ + bn*2 + 1] = proj1;
    out[OFF_POS  + bn*3 + 0] = pos0;
    out[OFF_POS  + bn*3 + 1] = pos1;
    out[OFF_POS  + bn*3 + 2] = pos2;
    out[OFF_RES  + bn*3 + 0] = res0;
    out[OFF_RES  + bn*3 + 1] = res1;
    out[OFF_RES  + bn*3 + 2] = res2;

    const float px0 = (proj0 + 0.5f) * (float)(BOX-1);
    const float px1 = (proj1 + 0.5f) * (float)(BOX-1);
    const int c0 = (int)fminf(fmaxf(floorf(px0 + 0.5f), 0.f), 255.f);
    const int c1 = (int)fminf(fmaxf(floorf(px1 + 0.5f), 0.f), 255.f);
    atomicAdd(&counts[b*CELLS + (c0>>2)*CELLS_X + (c1>>2)], 1);
}

// ---------------- kernel B: exclusive prefix scan of 4096 cells per image ----------------
__global__ __launch_bounds__(1024) void scan_cells(
    const int* __restrict__ counts, int* __restrict__ prefix, int* __restrict__ cursor)
{
    __shared__ int lds[1024];
    const int img = blockIdx.x, t = threadIdx.x;
    const int4 v = ((const int4*)(counts + img*CELLS))[t];
    const int s0 = v.x, s1 = s0 + v.y, s2 = s1 + v.z, s3 = s2 + v.w;
    lds[t] = s3;
    __syncthreads();
    #pragma unroll 1
    for (int off = 1; off < 1024; off <<= 1) {
        const int add = (t >= off) ? lds[t - off] : 0;
        __syncthreads();
        lds[t] += add;
        __syncthreads();
    }
    const int incl = lds[t];
    const int base = incl - s3;
    const int4 p = make_int4(base, base + s0, base + s1, base + s2);
    ((int4*)(prefix + img*PREF_STRIDE))[t] = p;
    ((int4*)(cursor + img*CELLS))[t] = p;
    if (t == 1023) prefix[img*PREF_STRIDE + CELLS] = incl;
}

// ---------------- kernel C: scatter point records into cell-sorted array ----------------
__global__ __launch_bounds__(ATPB) void scatter_pts(
    const float* __restrict__ z, const float* __restrict__ amp,
    const float* __restrict__ linamp_w, const float* __restrict__ linamp_b,
    const float* __restrict__ out, int* __restrict__ cursor, float4* __restrict__ recs)
{
    const int b = blockIdx.y;
    const int n = blockIdx.x*ATPB + threadIdx.x;
    if (n >= NPTS) return;

    const float ampv  = amp[0];
    const float zlast = z[b*LATD + LATD-1];
    const long long bn = (long long)b*NPTS + n;
    const float proj0 = out[OFF_PROJ + bn*2 + 0];
    const float proj1 = out[OFF_PROJ + bn*2 + 1];

    const float lo = fmaf(zlast, linamp_w[n], linamp_b[n]);
    const float a  = ampv / (1.0f + __expf(-lo));

    const float px0 = (proj0 + 0.5f) * (float)(BOX-1);
    const float px1 = (proj1 + 0.5f) * (float)(BOX-1);
    const int c0 = (int)fminf(fmaxf(floorf(px0 + 0.5f), 0.f), 255.f);
    const int c1 = (int)fminf(fmaxf(floorf(px1 + 0.5f), 0.f), 255.f);
    const int cell = (c0>>2)*CELLS_X + (c1>>2);

    const int idx = atomicAdd(&cursor[b*CELLS + cell], 1);
    recs[(long long)b*NPTS + idx] = make_float4(px0, px1, a, 0.f);
}

// ---------------- kernel D: emit fixed-size (cell, chunk) work items ----------------
__global__ __launch_bounds__(256) void build_work(
    const int* __restrict__ prefix, int* __restrict__ n_work, int* __restrict__ work)
{
    const int b = blockIdx.y;
    const int c = blockIdx.x*256 + threadIdx.x;
    const int* __restrict__ P = prefix + b*PREF_STRIDE;
    const int cnt = P[c+1] - P[c];
    if (cnt <= 0) return;
    const int nch = (cnt + CHUNK - 1)/CHUNK;
    const int base = atomicAdd(&n_work[b], nch);
    for (int k = 0; k < nch; k++) work[b*WCAP + base + k] = (c << 8) | k;
}

// -------- kernel E: one wave per 256-record chunk; lanes own 12x16 window --------
__global__ __launch_bounds__(256) void gather_work(
    const float4* __restrict__ recs, const int* __restrict__ prefix,
    const int* __restrict__ n_work, const int* __restrict__ work,
    float* __restrict__ out)
{
    const int b    = blockIdx.y;
    const int wave = blockIdx.x*4 + (threadIdx.x >> 6);   // 0..255
    const int lane = threadIdx.x & 63;
    const int nw   = n_work[b];

    const int* __restrict__ P = prefix + b*PREF_STRIDE;
    const float4* __restrict__ R = recs + (long long)b*NPTS;
    float* __restrict__ img = out + (size_t)b*BOX*BOX;
    const float Kc = -0.3205988f;   // -log2(e)/(2*1.5*1.5)

    for (int it = wave; it < nw; it += 256) {
        const int wd   = work[b*WCAP + it];
        const int cell = wd >> 8, kch = wd & 255;
        const int s = P[cell] + kch*CHUNK;
        const int e = min(P[cell+1], s + CHUNK);

        const int cy = cell >> 6, cx = cell & 63;
        const int col = lane & 15, r0 = lane >> 4;
        const int gx  = 4*cx - 4 + col;              // image col of this lane
        const int gy0 = 4*cy - 4 + r0;               // rows gy0, gy0+4, gy0+8
        const float xf  = (float)gx;
        const float y0f = (float)gy0, y1f = y0f + 4.f, y2f = y0f + 8.f;

        // preload up to 4 coalesced 64-record sub-blocks
        float4 rc[4];
        #pragma unroll
        for (int q = 0; q < 4; q++) {
            rc[q] = make_float4(0.f, 0.f, 0.f, 0.f);
            const int idx = s + q*64 + lane;
            if (idx < e) rc[q] = R[idx];
        }

        float a0 = 0.f, a1 = 0.f, a2 = 0.f;
        #pragma unroll
        for (int q = 0; q < 4; q++) {
            const int km = min(64, e - (s + q*64));
            for (int j = 0; j < km; ++j) {
                const float ry = bcast(rc[q].x, j);
                const float rx = bcast(rc[q].y, j);
                const float ra = bcast(rc[q].z, j);

                const float dx = xf - rx;
                float aex = ra * exp2f(dx*dx*Kc);
                aex = (dx <= 4.5f && dx > -4.5f) ? aex : 0.f;   // == tap-box mask

                const float dy0 = y0f - ry;
                const float dy1 = y1f - ry;
                const float dy2 = y2f - ry;
                float e0 = exp2f(dy0*dy0*Kc);
                float e1 = exp2f(dy1*dy1*Kc);
                float e2 = exp2f(dy2*dy2*Kc);
                e0 = (dy0 <= 4.5f && dy0 > -4.5f) ? e0 : 0.f;
                e1 = (dy1 <= 4.5f && dy1 > -4.5f) ? e1 : 0.f;
                e2 = (dy2 <= 4.5f && dy2 > -4.5f) ? e2 : 0.f;
                a0 = fmaf(e0, aex, a0);
                a1 = fmaf(e1, aex, a1);
                a2 = fmaf(e2, aex, a2);
            }
        }

        if (gx >= 0 && gx < BOX) {
            // gy0 in [-4, 251]: row0 needs >=0 check, row1 always in [0,255], row2 needs <256 check
            if (a0 != 0.f && gy0 >= 0)        atomicAdd(&img[ gy0     *BOX + gx], a0);
            if (a1 != 0.f)                    atomicAdd(&img[(gy0 + 4)*BOX + gx], a1);
            if (a2 != 0.f && gy0 + 8 < BOX)   atomicAdd(&img[(gy0 + 8)*BOX + gx], a2);
        }
    }
}

__global__ __launch_bounds__(256) void copy_img(const float4* __restrict__ src,
                                                float4* __restrict__ dst, int n4)
{
    int i = blockIdx.x*blockDim.x + threadIdx.x;
    if (i < n4) dst[i] = src[i];
}

extern "C" void kernel_launch(void* const* d_in, const int* in_sizes, int n_in,
                              void* d_out, int out_size, void* d_ws, size_t ws_size,
                              hipStream_t stream)
{
    const float* z        = (const float*)d_in[0];
    const float* r        = (const float*)d_in[1];
    const float* posp     = (const float*)d_in[2];
    const float* amp      = (const float*)d_in[3];
    const float* lin0_w   = (const float*)d_in[4];
    const float* deform_w = (const float*)d_in[5];
    const float* deform_b = (const float*)d_in[6];
    const float* lin1a_w  = (const float*)d_in[7];
    const float* lin1b_w  = (const float*)d_in[8];
    const float* linamp_w = (const float*)d_in[9];
    const float* linamp_b = (const float*)d_in[10];
    const int*   dflag    = (const int*)d_in[11];
    float* out = (float*)d_out;

    int* ws_i    = (int*)d_ws;
    int* counts  = ws_i + WS_COUNTS;
    int* n_work  = ws_i + WS_NWORK;
    int* prefix  = ws_i + WS_PREFIX;
    int* cursor  = ws_i + WS_CURSOR;
    int* work    = ws_i + WS_WORK;
    float4* recs = (float4*)((char*)d_ws + (size_t)WS_INTS*sizeof(int));

    // zero counts + n_work (contiguous) and the img accumulation region
    hipMemsetAsync(counts, 0, (size_t)(BATCH*CELLS + BATCH)*sizeof(int), stream);
    hipMemsetAsync(out, 0, (size_t)IMG_ELEMS*sizeof(float), stream);

    dim3 gridA(ABLKX, BATCH);
    mlp_fwd<<<gridA, ATPB, 0, stream>>>(z, r, posp, lin0_w, deform_w, deform_b,
                                        lin1a_w, lin1b_w, dflag, out, counts);

    scan_cells<<<BATCH, 1024, 0, stream>>>(counts, prefix, cursor);

    scatter_pts<<<gridA, ATPB, 0, stream>>>(z, amp, linamp_w, linamp_b,
                                            out, cursor, recs);

    dim3 gridW(CELLS/256, BATCH);
    build_work<<<gridW, 256, 0, stream>>>(prefix, n_work, work);

    dim3 gridG(64, BATCH);
    gather_work<<<gridG, 256, 0, stream>>>(recs, prefix, n_work, work, out);

    const int n4 = IMG_ELEMS/4;
    copy_img<<<(n4 + 255)/256, 256, 0, stream>>>((const float4*)out,
                                                 (float4*)(out + OFF_IMG2), n4);
}

// Round 9
// 308.948 us; speedup vs baseline: 9.5980x; 1.6102x over previous
//
#include <hip/hip_runtime.h>
#include <math.h>

#define BOX   256
#define NPTS  50000
#define LATD  10
#define NEUR  32
#define NLAY  3
#define BATCH 16

#define ATPB  256
#define ABLKX ((NPTS + ATPB - 1)/ATPB)     // 196

#define CELLS_X 64                          // 4x4-px cells
#define CELLS   (CELLS_X*CELLS_X)           // 4096 per image
#define PREF_STRIDE 4104
#define CHUNK   256                         // records per work item
#define WCAP    4608                        // work items cap per image

#define IMG_ELEMS (BATCH*BOX*BOX)
#define OFF_IMG2  (IMG_ELEMS)
#define OFF_PROJ  (2*IMG_ELEMS)
#define OFF_POS   (OFF_PROJ + BATCH*NPTS*2)
#define OFF_RES   (OFF_POS  + BATCH*NPTS*3)

// ws ints: counts[16*4096] | n_work[16] | prefix[16*4104] | cursor[16*4096] | work[16*4608]
// then (16B aligned): recs float4[16*50000]  -> ~13.9 MB total
#define WS_COUNTS 0
#define WS_NWORK  (BATCH*CELLS)
#define WS_PREFIX (WS_NWORK + BATCH)
#define WS_CURSOR (WS_PREFIX + BATCH*PREF_STRIDE)
#define WS_WORK   (WS_CURSOR + BATCH*CELLS)
#define WS_INTS   (WS_WORK + BATCH*WCAP)

__device__ __forceinline__ float fast_tanh(float x) {
    return 1.0f - 2.0f / (__expf(2.0f * x) + 1.0f);
}
__device__ __forceinline__ float bcast(float v, int j) {
    return __int_as_float(__builtin_amdgcn_readlane(__float_as_int(v), j));
}

// ------- kernel A: per-point MLP + outputs + block-aggregated cell counts -------
__global__ __launch_bounds__(ATPB) void mlp_fwd(
    const float* __restrict__ z, const float* __restrict__ r,
    const float* __restrict__ pos_param,
    const float* __restrict__ lin0_w, const float* __restrict__ deform_w,
    const float* __restrict__ deform_b, const float* __restrict__ lin1a_w,
    const float* __restrict__ lin1b_w, const int* __restrict__ dflag,
    float* __restrict__ out, int* __restrict__ counts)
{
    __shared__ float s_zpart[NEUR];
    __shared__ int   s_cnt[CELLS];          // 16 KB block histogram
    const int b = blockIdx.y, tid = threadIdx.x;

    for (int i = tid; i < CELLS; i += ATPB) s_cnt[i] = 0;
    if (tid < NEUR) {
        float acc = 0.f;
        #pragma unroll
        for (int j = 0; j < LATD-1; j++)
            acc = fmaf(lin0_w[tid*12 + 3 + j], z[b*LATD + j], acc);
        s_zpart[tid] = acc;
    }
    __syncthreads();

    const int n = blockIdx.x*ATPB + tid;
    if (n < NPTS) {
        const int dd = *dflag;

        const float r00 = r[b*9+0], r01 = r[b*9+1];
        const float r10 = r[b*9+3], r11 = r[b*9+4];
        const float r20 = r[b*9+6], r21 = r[b*9+7];

        const float p0 = pos_param[n*3+0];
        const float p1 = pos_param[n*3+1];
        const float p2 = pos_param[n*3+2];

        float res0 = 0.f, res1 = 0.f, res2 = 0.f;
        if (dd > 0) {
            float h[NEUR], nh[NEUR];
            #pragma unroll
            for (int o = 0; o < NEUR; o++) {
                float acc = s_zpart[o];
                acc = fmaf(lin0_w[o*12+0], p0, acc);
                acc = fmaf(lin0_w[o*12+1], p1, acc);
                acc = fmaf(lin0_w[o*12+2], p2, acc);
                h[o] = acc;
            }
            #pragma unroll 1
            for (int l = 0; l < NLAY; l++) {
                const float* __restrict__ W  = deform_w + l*NEUR*NEUR;
                const float* __restrict__ bb = deform_b + l*NEUR;
                #pragma unroll
                for (int o = 0; o < NEUR; o++) {
                    float acc = bb[o];
                    #pragma unroll
                    for (int j = 0; j < NEUR; j++)
                        acc = fmaf(W[o*NEUR + j], h[j], acc);
                    nh[o] = fmaxf(acc, 0.f) + h[o];
                }
                #pragma unroll
                for (int o = 0; o < NEUR; o++) h[o] = nh[o];
            }
            float t0 = 0.f, t1 = 0.f, t2 = 0.f;
            #pragma unroll
            for (int j = 0; j < NEUR; j++) {
                t0 = fmaf(lin1a_w[0*NEUR + j], h[j], t0);
                t1 = fmaf(lin1a_w[1*NEUR + j], h[j], t1);
                t2 = fmaf(lin1a_w[2*NEUR + j], h[j], t2);
            }
            t0 = fast_tanh(t0); t1 = fast_tanh(t1); t2 = fast_tanh(t2);
            res0 = fmaf(t0, lin1b_w[0], fmaf(t1, lin1b_w[1], t2*lin1b_w[2]));
            res1 = fmaf(t0, lin1b_w[3], fmaf(t1, lin1b_w[4], t2*lin1b_w[5]));
            res2 = fmaf(t0, lin1b_w[6], fmaf(t1, lin1b_w[7], t2*lin1b_w[8]));
        }

        const float pos0 = p0 + res0, pos1 = p1 + res1, pos2 = p2 + res2;
        const float proj0 = fmaf(pos0, r00, fmaf(pos1, r10, pos2*r20));
        const float proj1 = fmaf(pos0, r01, fmaf(pos1, r11, pos2*r21));

        const long long bn = (long long)b*NPTS + n;
        out[OFF_PROJ + bn*2 + 0] = proj0;
        out[OFF_PROJ + bn*2 + 1] = proj1;
        out[OFF_POS  + bn*3 + 0] = pos0;
        out[OFF_POS  + bn*3 + 1] = pos1;
        out[OFF_POS  + bn*3 + 2] = pos2;
        out[OFF_RES  + bn*3 + 0] = res0;
        out[OFF_RES  + bn*3 + 1] = res1;
        out[OFF_RES  + bn*3 + 2] = res2;

        const float px0 = (proj0 + 0.5f) * (float)(BOX-1);
        const float px1 = (proj1 + 0.5f) * (float)(BOX-1);
        const int c0 = (int)fminf(fmaxf(floorf(px0 + 0.5f), 0.f), 255.f);
        const int c1 = (int)fminf(fmaxf(floorf(px1 + 0.5f), 0.f), 255.f);
        atomicAdd(&s_cnt[(c0>>2)*CELLS_X + (c1>>2)], 1);     // LDS atomic
    }
    __syncthreads();
    // one global atomic per non-empty cell per block
    for (int c = tid; c < CELLS; c += ATPB) {
        const int cnt = s_cnt[c];
        if (cnt > 0) atomicAdd(&counts[b*CELLS + c], cnt);
    }
}

// ---------------- kernel B: exclusive prefix scan of 4096 cells per image ----------------
__global__ __launch_bounds__(1024) void scan_cells(
    const int* __restrict__ counts, int* __restrict__ prefix, int* __restrict__ cursor)
{
    __shared__ int lds[1024];
    const int img = blockIdx.x, t = threadIdx.x;
    const int4 v = ((const int4*)(counts + img*CELLS))[t];
    const int s0 = v.x, s1 = s0 + v.y, s2 = s1 + v.z, s3 = s2 + v.w;
    lds[t] = s3;
    __syncthreads();
    #pragma unroll 1
    for (int off = 1; off < 1024; off <<= 1) {
        const int add = (t >= off) ? lds[t - off] : 0;
        __syncthreads();
        lds[t] += add;
        __syncthreads();
    }
    const int incl = lds[t];
    const int base = incl - s3;
    const int4 p = make_int4(base, base + s0, base + s1, base + s2);
    ((int4*)(prefix + img*PREF_STRIDE))[t] = p;
    ((int4*)(cursor + img*CELLS))[t] = p;
    if (t == 1023) prefix[img*PREF_STRIDE + CELLS] = incl;
}

// ------- kernel C: scatter with block-aggregated cursor claims -------
__global__ __launch_bounds__(ATPB) void scatter_pts(
    const float* __restrict__ z, const float* __restrict__ amp,
    const float* __restrict__ linamp_w, const float* __restrict__ linamp_b,
    const float* __restrict__ out, int* __restrict__ cursor, float4* __restrict__ recs)
{
    __shared__ int s_cnt[CELLS];    // 16 KB
    __shared__ int s_base[CELLS];   // 16 KB
    const int b = blockIdx.y, tid = threadIdx.x;
    for (int i = tid; i < CELLS; i += ATPB) s_cnt[i] = 0;
    __syncthreads();

    const int n = blockIdx.x*ATPB + tid;
    int cell = 0, rank = 0;
    float4 rec = make_float4(0.f, 0.f, 0.f, 0.f);
    if (n < NPTS) {
        const float ampv  = amp[0];
        const float zlast = z[b*LATD + LATD-1];
        const long long bn = (long long)b*NPTS + n;
        const float proj0 = out[OFF_PROJ + bn*2 + 0];
        const float proj1 = out[OFF_PROJ + bn*2 + 1];

        const float lo = fmaf(zlast, linamp_w[n], linamp_b[n]);
        const float a  = ampv / (1.0f + __expf(-lo));

        const float px0 = (proj0 + 0.5f) * (float)(BOX-1);
        const float px1 = (proj1 + 0.5f) * (float)(BOX-1);
        const int c0 = (int)fminf(fmaxf(floorf(px0 + 0.5f), 0.f), 255.f);
        const int c1 = (int)fminf(fmaxf(floorf(px1 + 0.5f), 0.f), 255.f);
        cell = (c0>>2)*CELLS_X + (c1>>2);
        rec  = make_float4(px0, px1, a, 0.f);
        rank = atomicAdd(&s_cnt[cell], 1);                   // LDS atomic
    }
    __syncthreads();
    for (int c = tid; c < CELLS; c += ATPB) {
        const int cnt = s_cnt[c];
        if (cnt > 0) s_base[c] = atomicAdd(&cursor[b*CELLS + c], cnt);
    }
    __syncthreads();
    if (n < NPTS)
        recs[(long long)b*NPTS + s_base[cell] + rank] = rec;
}

// ---------------- kernel D: emit fixed-size (cell, chunk) work items ----------------
__global__ __launch_bounds__(256) void build_work(
    const int* __restrict__ prefix, int* __restrict__ n_work, int* __restrict__ work)
{
    const int b = blockIdx.y;
    const int c = blockIdx.x*256 + threadIdx.x;
    const int* __restrict__ P = prefix + b*PREF_STRIDE;
    const int cnt = P[c+1] - P[c];
    if (cnt <= 0) return;
    const int nch = (cnt + CHUNK - 1)/CHUNK;
    const int base = atomicAdd(&n_work[b], nch);
    for (int k = 0; k < nch; k++) work[b*WCAP + base + k] = (c << 8) | k;
}

// -------- kernel E: one wave per 256-record chunk; lanes own 12x16 window --------
__global__ __launch_bounds__(256) void gather_work(
    const float4* __restrict__ recs, const int* __restrict__ prefix,
    const int* __restrict__ n_work, const int* __restrict__ work,
    float* __restrict__ out)
{
    const int b    = blockIdx.y;
    const int wave = blockIdx.x*4 + (threadIdx.x >> 6);   // 0..255
    const int lane = threadIdx.x & 63;
    const int nw   = n_work[b];

    const int* __restrict__ P = prefix + b*PREF_STRIDE;
    const float4* __restrict__ R = recs + (long long)b*NPTS;
    float* __restrict__ img = out + (size_t)b*BOX*BOX;
    const float Kc = -0.3205988f;   // -log2(e)/(2*1.5*1.5)

    for (int it = wave; it < nw; it += 256) {
        const int wd   = work[b*WCAP + it];
        const int cell = wd >> 8, kch = wd & 255;
        const int s = P[cell] + kch*CHUNK;
        const int e = min(P[cell+1], s + CHUNK);

        const int cy = cell >> 6, cx = cell & 63;
        const int col = lane & 15, r0 = lane >> 4;
        const int gx  = 4*cx - 4 + col;
        const int gy0 = 4*cy - 4 + r0;
        const float xf  = (float)gx;
        const float y0f = (float)gy0, y1f = y0f + 4.f, y2f = y0f + 8.f;

        float4 rc[4];
        #pragma unroll
        for (int q = 0; q < 4; q++) {
            rc[q] = make_float4(0.f, 0.f, 0.f, 0.f);
            const int idx = s + q*64 + lane;
            if (idx < e) rc[q] = R[idx];
        }

        float a0 = 0.f, a1 = 0.f, a2 = 0.f;
        #pragma unroll
        for (int q = 0; q < 4; q++) {
            const int km = min(64, e - (s + q*64));
            for (int j = 0; j < km; ++j) {
                const float ry = bcast(rc[q].x, j);
                const float rx = bcast(rc[q].y, j);
                const float ra = bcast(rc[q].z, j);

                const float dx = xf - rx;
                float aex = ra * exp2f(dx*dx*Kc);
                aex = (dx <= 4.5f && dx > -4.5f) ? aex : 0.f;

                const float dy0 = y0f - ry;
                const float dy1 = y1f - ry;
                const float dy2 = y2f - ry;
                float e0 = exp2f(dy0*dy0*Kc);
                float e1 = exp2f(dy1*dy1*Kc);
                float e2 = exp2f(dy2*dy2*Kc);
                e0 = (dy0 <= 4.5f && dy0 > -4.5f) ? e0 : 0.f;
                e1 = (dy1 <= 4.5f && dy1 > -4.5f) ? e1 : 0.f;
                e2 = (dy2 <= 4.5f && dy2 > -4.5f) ? e2 : 0.f;
                a0 = fmaf(e0, aex, a0);
                a1 = fmaf(e1, aex, a1);
                a2 = fmaf(e2, aex, a2);
            }
        }

        if (gx >= 0 && gx < BOX) {
            if (a0 != 0.f && gy0 >= 0)        atomicAdd(&img[ gy0     *BOX + gx], a0);
            if (a1 != 0.f)                    atomicAdd(&img[(gy0 + 4)*BOX + gx], a1);
            if (a2 != 0.f && gy0 + 8 < BOX)   atomicAdd(&img[(gy0 + 8)*BOX + gx], a2);
        }
    }
}

__global__ __launch_bounds__(256) void copy_img(const float4* __restrict__ src,
                                                float4* __restrict__ dst, int n4)
{
    int i = blockIdx.x*blockDim.x + threadIdx.x;
    if (i < n4) dst[i] = src[i];
}

extern "C" void kernel_launch(void* const* d_in, const int* in_sizes, int n_in,
                              void* d_out, int out_size, void* d_ws, size_t ws_size,
                              hipStream_t stream)
{
    const float* z        = (const float*)d_in[0];
    const float* r        = (const float*)d_in[1];
    const float* posp     = (const float*)d_in[2];
    const float* amp      = (const float*)d_in[3];
    const float* lin0_w   = (const float*)d_in[4];
    const float* deform_w = (const float*)d_in[5];
    const float* deform_b = (const float*)d_in[6];
    const float* lin1a_w  = (const float*)d_in[7];
    const float* lin1b_w  = (const float*)d_in[8];
    const float* linamp_w = (const float*)d_in[9];
    const float* linamp_b = (const float*)d_in[10];
    const int*   dflag    = (const int*)d_in[11];
    float* out = (float*)d_out;

    int* ws_i    = (int*)d_ws;
    int* counts  = ws_i + WS_COUNTS;
    int* n_work  = ws_i + WS_NWORK;
    int* prefix  = ws_i + WS_PREFIX;
    int* cursor  = ws_i + WS_CURSOR;
    int* work    = ws_i + WS_WORK;
    float4* recs = (float4*)((char*)d_ws + (size_t)WS_INTS*sizeof(int));

    hipMemsetAsync(counts, 0, (size_t)(BATCH*CELLS + BATCH)*sizeof(int), stream);
    hipMemsetAsync(out, 0, (size_t)IMG_ELEMS*sizeof(float), stream);

    dim3 gridA(ABLKX, BATCH);
    mlp_fwd<<<gridA, ATPB, 0, stream>>>(z, r, posp, lin0_w, deform_w, deform_b,
                                        lin1a_w, lin1b_w, dflag, out, counts);

    scan_cells<<<BATCH, 1024, 0, stream>>>(counts, prefix, cursor);

    scatter_pts<<<gridA, ATPB, 0, stream>>>(z, amp, linamp_w, linamp_b,
                                            out, cursor, recs);

    dim3 gridW(CELLS/256, BATCH);
    build_work<<<gridW, 256, 0, stream>>>(prefix, n_work, work);

    dim3 gridG(64, BATCH);
    gather_work<<<gridG, 256, 0, stream>>>(recs, prefix, n_work, work, out);

    const int n4 = IMG_ELEMS/4;
    copy_img<<<(n4 + 255)/256, 256, 0, stream>>>((const float4*)out,
                                                 (float4*)(out + OFF_IMG2), n4);
}

// Round 10
// 297.530 us; speedup vs baseline: 9.9664x; 1.0384x over previous
//
#include <hip/hip_runtime.h>
#include <math.h>

#define BOX   256
#define NPTS  50000
#define LATD  10
#define NEUR  32
#define NLAY  3
#define BATCH 16

#define MTPB  256
#define MPPT  2
#define MPTS  (MTPB*MPPT)                  // 512 points per mlp block
#define MBLKX ((NPTS + MPTS - 1)/MPTS)     // 98

#define PTPB  256
#define PBLKX ((NPTS + PTPB - 1)/PTPB)     // 196

#define CELLS_X 64                          // 4x4-px cells
#define CELLS   (CELLS_X*CELLS_X)           // 4096
#define PREF_STRIDE 4104
#define CHUNK   256
#define WCAP    4608

#define IMG_ELEMS (BATCH*BOX*BOX)
#define OFF_IMG2  (IMG_ELEMS)
#define OFF_PROJ  (2*IMG_ELEMS)
#define OFF_POS   (OFF_PROJ + BATCH*NPTS*2)
#define OFF_RES   (OFF_POS  + BATCH*NPTS*3)

// ws ints: counts[16*4096] | n_work[16] | prefix[16*4104] | work[16*4608] | aux[16*50000]
// then (16B aligned): recs float4[16*50000]   -> ~16.8 MB total
#define WS_COUNTS 0
#define WS_NWORK  (BATCH*CELLS)                    // 65536
#define WS_PREFIX (WS_NWORK + BATCH)               // 65552
#define WS_WORK   (WS_PREFIX + BATCH*PREF_STRIDE)  // 131216
#define WS_AUX    (WS_WORK + BATCH*WCAP)           // 204944
#define WS_INTS   (WS_AUX + BATCH*NPTS)            // 1004944 ints (x4 B, 16B-aligned)

__device__ __forceinline__ float fast_tanh(float x) {
    return 1.0f - 2.0f / (__expf(2.0f * x) + 1.0f);
}

// ---- kernel A: fused MLP (2 pts/thread) + outputs + histogram + base claim ----
__global__ __launch_bounds__(MTPB) void mlp_bin(
    const float* __restrict__ z, const float* __restrict__ r,
    const float* __restrict__ pos_param, const float* __restrict__ amp,
    const float* __restrict__ lin0_w, const float* __restrict__ deform_w,
    const float* __restrict__ deform_b, const float* __restrict__ lin1a_w,
    const float* __restrict__ lin1b_w, const float* __restrict__ linamp_w,
    const float* __restrict__ linamp_b, const int* __restrict__ dflag,
    float* __restrict__ out, int* __restrict__ counts, int* __restrict__ aux)
{
    __shared__ float s_zpart[NEUR];
    __shared__ int   s_cnt[CELLS];          // 16 KB histogram -> then bases
    const int b = blockIdx.y, tid = threadIdx.x;

    for (int i = tid; i < CELLS; i += MTPB) s_cnt[i] = 0;
    if (tid < NEUR) {
        float acc = 0.f;
        #pragma unroll
        for (int j = 0; j < LATD-1; j++)
            acc = fmaf(lin0_w[tid*12 + 3 + j], z[b*LATD + j], acc);
        s_zpart[tid] = acc;
    }
    __syncthreads();

    const int n0 = blockIdx.x*MPTS + tid;
    const int n1 = n0 + MTPB;
    const bool v0 = (n0 < NPTS), v1 = (n1 < NPTS);
    const int m0 = v0 ? n0 : 0, m1 = v1 ? n1 : 0;
    const int dd = *dflag;

    const float r00 = r[b*9+0], r01 = r[b*9+1];
    const float r10 = r[b*9+3], r11 = r[b*9+4];
    const float r20 = r[b*9+6], r21 = r[b*9+7];
    const float zlast = z[b*LATD + LATD-1];
    const float ampv  = amp[0];

    const float p00 = pos_param[m0*3+0], p01 = pos_param[m0*3+1], p02 = pos_param[m0*3+2];
    const float p10 = pos_param[m1*3+0], p11 = pos_param[m1*3+1], p12 = pos_param[m1*3+2];

    float res00=0.f, res01=0.f, res02=0.f, res10=0.f, res11=0.f, res12=0.f;
    if (dd > 0) {
        float h0[NEUR], h1[NEUR];
        #pragma unroll
        for (int o = 0; o < NEUR; o++) {
            const float w0 = lin0_w[o*12+0], w1 = lin0_w[o*12+1], w2 = lin0_w[o*12+2];
            h0[o] = fmaf(w0,p00, fmaf(w1,p01, fmaf(w2,p02, s_zpart[o])));
            h1[o] = fmaf(w0,p10, fmaf(w1,p11, fmaf(w2,p12, s_zpart[o])));
        }
        #pragma unroll 1
        for (int l = 0; l < NLAY; l++) {
            const float* __restrict__ W  = deform_w + l*NEUR*NEUR;
            const float* __restrict__ bb = deform_b + l*NEUR;
            float g0[NEUR], g1[NEUR];
            #pragma unroll
            for (int o = 0; o < NEUR; o++) {
                float a0 = bb[o], a1 = a0;
                #pragma unroll
                for (int j = 0; j < NEUR; j++) {
                    const float w = W[o*NEUR + j];
                    a0 = fmaf(w, h0[j], a0);
                    a1 = fmaf(w, h1[j], a1);
                }
                g0[o] = fmaxf(a0, 0.f) + h0[o];
                g1[o] = fmaxf(a1, 0.f) + h1[o];
            }
            #pragma unroll
            for (int o = 0; o < NEUR; o++) { h0[o] = g0[o]; h1[o] = g1[o]; }
        }
        float t00=0.f,t01=0.f,t02=0.f,t10=0.f,t11=0.f,t12=0.f;
        #pragma unroll
        for (int j = 0; j < NEUR; j++) {
            const float wa = lin1a_w[0*NEUR+j], wb = lin1a_w[1*NEUR+j], wc = lin1a_w[2*NEUR+j];
            t00 = fmaf(wa, h0[j], t00);  t10 = fmaf(wa, h1[j], t10);
            t01 = fmaf(wb, h0[j], t01);  t11 = fmaf(wb, h1[j], t11);
            t02 = fmaf(wc, h0[j], t02);  t12 = fmaf(wc, h1[j], t12);
        }
        t00 = fast_tanh(t00); t01 = fast_tanh(t01); t02 = fast_tanh(t02);
        t10 = fast_tanh(t10); t11 = fast_tanh(t11); t12 = fast_tanh(t12);
        res00 = fmaf(t00, lin1b_w[0], fmaf(t01, lin1b_w[1], t02*lin1b_w[2]));
        res01 = fmaf(t00, lin1b_w[3], fmaf(t01, lin1b_w[4], t02*lin1b_w[5]));
        res02 = fmaf(t00, lin1b_w[6], fmaf(t01, lin1b_w[7], t02*lin1b_w[8]));
        res10 = fmaf(t10, lin1b_w[0], fmaf(t11, lin1b_w[1], t12*lin1b_w[2]));
        res11 = fmaf(t10, lin1b_w[3], fmaf(t11, lin1b_w[4], t12*lin1b_w[5]));
        res12 = fmaf(t10, lin1b_w[6], fmaf(t11, lin1b_w[7], t12*lin1b_w[8]));
    }

    int cell0 = 0, cell1 = 0, rank0 = 0, rank1 = 0;

    // ---- epilogue point 0 ----
    if (v0) {
        const float pos0 = p00 + res00, pos1 = p01 + res01, pos2 = p02 + res02;
        const float pj0 = fmaf(pos0, r00, fmaf(pos1, r10, pos2*r20));
        const float pj1 = fmaf(pos0, r01, fmaf(pos1, r11, pos2*r21));
        const long long bn = (long long)b*NPTS + n0;
        out[OFF_PROJ + bn*2 + 0] = pj0;  out[OFF_PROJ + bn*2 + 1] = pj1;
        out[OFF_POS  + bn*3 + 0] = pos0; out[OFF_POS  + bn*3 + 1] = pos1;
        out[OFF_POS  + bn*3 + 2] = pos2;
        out[OFF_RES  + bn*3 + 0] = res00; out[OFF_RES + bn*3 + 1] = res01;
        out[OFF_RES  + bn*3 + 2] = res02;
        const float px0 = (pj0 + 0.5f) * (float)(BOX-1);
        const float px1 = (pj1 + 0.5f) * (float)(BOX-1);
        const int c0 = (int)fminf(fmaxf(floorf(px0 + 0.5f), 0.f), 255.f);
        const int c1 = (int)fminf(fmaxf(floorf(px1 + 0.5f), 0.f), 255.f);
        cell0 = (c0>>2)*CELLS_X + (c1>>2);
        rank0 = atomicAdd(&s_cnt[cell0], 1);
    }
    // ---- epilogue point 1 ----
    if (v1) {
        const float pos0 = p10 + res10, pos1 = p11 + res11, pos2 = p12 + res12;
        const float pj0 = fmaf(pos0, r00, fmaf(pos1, r10, pos2*r20));
        const float pj1 = fmaf(pos0, r01, fmaf(pos1, r11, pos2*r21));
        const long long bn = (long long)b*NPTS + n1;
        out[OFF_PROJ + bn*2 + 0] = pj0;  out[OFF_PROJ + bn*2 + 1] = pj1;
        out[OFF_POS  + bn*3 + 0] = pos0; out[OFF_POS  + bn*3 + 1] = pos1;
        out[OFF_POS  + bn*3 + 2] = pos2;
        out[OFF_RES  + bn*3 + 0] = res10; out[OFF_RES + bn*3 + 1] = res11;
        out[OFF_RES  + bn*3 + 2] = res12;
        const float px0 = (pj0 + 0.5f) * (float)(BOX-1);
        const float px1 = (pj1 + 0.5f) * (float)(BOX-1);
        const int c0 = (int)fminf(fmaxf(floorf(px0 + 0.5f), 0.f), 255.f);
        const int c1 = (int)fminf(fmaxf(floorf(px1 + 0.5f), 0.f), 255.f);
        cell1 = (c0>>2)*CELLS_X + (c1>>2);
        rank1 = atomicAdd(&s_cnt[cell1], 1);
    }
    __syncthreads();
    // claim global bases: one atomic per non-empty cell per block; s_cnt becomes base
    for (int c = tid; c < CELLS; c += MTPB) {
        const int cnt = s_cnt[c];
        if (cnt > 0) s_cnt[c] = atomicAdd(&counts[b*CELLS + c], cnt);
    }
    __syncthreads();
    if (v0) aux[b*NPTS + n0] = (cell0 << 16) | (s_cnt[cell0] + rank0);
    if (v1) aux[b*NPTS + n1] = (cell1 << 16) | (s_cnt[cell1] + rank1);
}

// ---------------- kernel B: exclusive prefix scan of 4096 cells per image ----------------
__global__ __launch_bounds__(1024) void scan_cells(
    const int* __restrict__ counts, int* __restrict__ prefix)
{
    __shared__ int lds[1024];
    const int img = blockIdx.x, t = threadIdx.x;
    const int4 v = ((const int4*)(counts + img*CELLS))[t];
    const int s0 = v.x, s1 = s0 + v.y, s2 = s1 + v.z, s3 = s2 + v.w;
    lds[t] = s3;
    __syncthreads();
    #pragma unroll 1
    for (int off = 1; off < 1024; off <<= 1) {
        const int add = (t >= off) ? lds[t - off] : 0;
        __syncthreads();
        lds[t] += add;
        __syncthreads();
    }
    const int incl = lds[t];
    const int base = incl - s3;
    ((int4*)(prefix + img*PREF_STRIDE))[t] = make_int4(base, base+s0, base+s1, base+s2);
    if (t == 1023) prefix[img*PREF_STRIDE + CELLS] = incl;
}

// ------- kernel C: place records at final cell-sorted positions -------
__global__ __launch_bounds__(PTPB) void place(
    const float* __restrict__ z, const float* __restrict__ amp,
    const float* __restrict__ linamp_w, const float* __restrict__ linamp_b,
    const float* __restrict__ out, const int* __restrict__ prefix,
    const int* __restrict__ aux, float4* __restrict__ recs)
{
    const int b = blockIdx.y;
    const int n = blockIdx.x*PTPB + threadIdx.x;
    if (n >= NPTS) return;

    const long long bn = (long long)b*NPTS + n;
    const float pj0 = out[OFF_PROJ + bn*2 + 0];
    const float pj1 = out[OFF_PROJ + bn*2 + 1];
    const float lo = fmaf(z[b*LATD + LATD-1], linamp_w[n], linamp_b[n]);
    const float a  = amp[0] / (1.0f + __expf(-lo));
    const float px0 = (pj0 + 0.5f) * (float)(BOX-1);
    const float px1 = (pj1 + 0.5f) * (float)(BOX-1);

    const int av  = aux[b*NPTS + n];
    const int cell = av >> 16, wr = av & 0xFFFF;
    const int dst  = prefix[b*PREF_STRIDE + cell] + wr;
    recs[(long long)b*NPTS + dst] = make_float4(px0, px1, a, 0.f);
}

// ---------------- kernel D: emit fixed-size (cell, chunk) work items ----------------
__global__ __launch_bounds__(256) void build_work(
    const int* __restrict__ prefix, int* __restrict__ n_work, int* __restrict__ work)
{
    const int b = blockIdx.y;
    const int c = blockIdx.x*256 + threadIdx.x;
    const int* __restrict__ P = prefix + b*PREF_STRIDE;
    const int cnt = P[c+1] - P[c];
    if (cnt <= 0) return;
    const int nch = (cnt + CHUNK - 1)/CHUNK;
    const int base = atomicAdd(&n_work[b], nch);
    for (int k = 0; k < nch; k++) work[b*WCAP + base + k] = (c << 8) | k;
}

// -------- kernel E: one wave per chunk; scalar record loads; 2-exp + int masks --------
__global__ __launch_bounds__(256) void gather_work(
    const float4* __restrict__ recs, const int* __restrict__ prefix,
    const int* __restrict__ n_work, const int* __restrict__ work,
    float* __restrict__ out)
{
    const int b    = blockIdx.y;
    const int wave = blockIdx.x*4 + (threadIdx.x >> 6);   // 0..255
    const int lane = threadIdx.x & 63;
    const int nw   = n_work[b];

    const int* __restrict__ P = prefix + b*PREF_STRIDE;
    const float4* __restrict__ R = recs + (long long)b*NPTS;
    float* __restrict__ img = out + (size_t)b*BOX*BOX;
    const float Kc  = -0.32059884f;                // -log2(e)/(2*sig^2)
    const float K8  = 8.0f  * Kc;
    const float K16 = 16.0f * Kc;
    const float C32 = 0.00081582472f;              // 2^(32*Kc)

    for (int it = wave; it < nw; it += 256) {
        const int wd   = __builtin_amdgcn_readfirstlane(work[b*WCAP + it]);
        const int cell = wd >> 8, kch = wd & 255;
        const int s = P[cell] + kch*CHUNK;          // scalar (cell uniform)
        const int e = min(P[cell+1], s + CHUNK);

        const int cy = cell >> 6, cx = cell & 63;
        const int col = lane & 15, r0 = lane >> 4;
        const int gx  = 4*cx - 4 + col;
        const int gy0 = 4*cy - 4 + r0;
        const float xf  = (float)gx;
        const float y0f = (float)gy0;
        const float fr0 = (float)r0;
        const float cy4 = (float)(4*cy);

        float a0 = 0.f, a1 = 0.f, a2 = 0.f;
        #pragma unroll 2
        for (int rr = s; rr < e; ++rr) {
            const float4 rc = R[rr];                // uniform addr -> s_load_dwordx4
            const float ry = rc.x, rx = rc.y, ra = rc.z;

            // x: weight + exact tap-box mask
            const float dx = xf - rx;
            float aex = ra * exp2f((dx*dx)*Kc);
            aex = (dx > -4.5f && dx <= 4.5f) ? aex : 0.f;

            // y: one exp + shift identity; integer-window masks
            const float dy = y0f - ry;
            const float e0 = exp2f((dy*dy)*Kc);
            const float u  = exp2f(fmaf(dy, K8, K16));
            const float e1 = e0 * u;
            const float e2 = e1 * (u * C32);
            const float st = floorf(ry + 0.5f) - cy4;    // 0..3 for interior recs
            const float w0 = (fr0 >= st) ? e0 : 0.f;
            const float w2 = (fr0 <= st) ? e2 : 0.f;
            a0 = fmaf(w0, aex, a0);
            a1 = fmaf(e1, aex, a1);                      // middle rows always in-box
            a2 = fmaf(w2, aex, a2);
        }

        if (gx >= 0 && gx < BOX) {
            if (a0 != 0.f && gy0 >= 0)      atomicAdd(&img[ gy0     *BOX + gx], a0);
            if (a1 != 0.f)                  atomicAdd(&img[(gy0 + 4)*BOX + gx], a1);
            if (a2 != 0.f && gy0 + 8 < BOX) atomicAdd(&img[(gy0 + 8)*BOX + gx], a2);
        }
    }
}

__global__ __launch_bounds__(256) void copy_img(const float4* __restrict__ src,
                                                float4* __restrict__ dst, int n4)
{
    int i = blockIdx.x*blockDim.x + threadIdx.x;
    if (i < n4) dst[i] = src[i];
}

extern "C" void kernel_launch(void* const* d_in, const int* in_sizes, int n_in,
                              void* d_out, int out_size, void* d_ws, size_t ws_size,
                              hipStream_t stream)
{
    const float* z        = (const float*)d_in[0];
    const float* r        = (const float*)d_in[1];
    const float* posp     = (const float*)d_in[2];
    const float* amp      = (const float*)d_in[3];
    const float* lin0_w   = (const float*)d_in[4];
    const float* deform_w = (const float*)d_in[5];
    const float* deform_b = (const float*)d_in[6];
    const float* lin1a_w  = (const float*)d_in[7];
    const float* lin1b_w  = (const float*)d_in[8];
    const float* linamp_w = (const float*)d_in[9];
    const float* linamp_b = (const float*)d_in[10];
    const int*   dflag    = (const int*)d_in[11];
    float* out = (float*)d_out;

    int* ws_i    = (int*)d_ws;
    int* counts  = ws_i + WS_COUNTS;
    int* n_work  = ws_i + WS_NWORK;
    int* prefix  = ws_i + WS_PREFIX;
    int* work    = ws_i + WS_WORK;
    int* aux     = ws_i + WS_AUX;
    float4* recs = (float4*)((char*)d_ws + (size_t)WS_INTS*sizeof(int));

    hipMemsetAsync(counts, 0, (size_t)(BATCH*CELLS + BATCH)*sizeof(int), stream);
    hipMemsetAsync(out, 0, (size_t)IMG_ELEMS*sizeof(float), stream);

    dim3 gridM(MBLKX, BATCH);
    mlp_bin<<<gridM, MTPB, 0, stream>>>(z, r, posp, amp, lin0_w, deform_w, deform_b,
                                        lin1a_w, lin1b_w, linamp_w, linamp_b, dflag,
                                        out, counts, aux);

    scan_cells<<<BATCH, 1024, 0, stream>>>(counts, prefix);

    dim3 gridP(PBLKX, BATCH);
    place<<<gridP, PTPB, 0, stream>>>(z, amp, linamp_w, linamp_b, out, prefix, aux, recs);

    dim3 gridW(CELLS/256, BATCH);
    build_work<<<gridW, 256, 0, stream>>>(prefix, n_work, work);

    dim3 gridG(64, BATCH);
    gather_work<<<gridG, 256, 0, stream>>>(recs, prefix, n_work, work, out);

    const int n4 = IMG_ELEMS/4;
    copy_img<<<(n4 + 255)/256, 256, 0, stream>>>((const float4*)out,
                                                 (float4*)(out + OFF_IMG2), n4);
}